// Round 15
// baseline (295.989 us; speedup 1.0000x reference)
//
#include <hip/hip_runtime.h>

typedef _Float16 f16;
typedef f16 f16x8 __attribute__((ext_vector_type(8)));
typedef f16 f16x4 __attribute__((ext_vector_type(4)));
typedef float f32x4 __attribute__((ext_vector_type(4)));

#define S_LEN 2048
#define D_MODEL 2048
#define NHEADS 8
#define DQ 128
#define DV 256
#define NCOL 6144   // q(1024) | k(1024) | v(2048) | og(2048)
#define QOFF 0
#define KOFF 1024
#define VOFF 2048
#define OGOFF 4096
#define NROWS 4096  // B*S
#define CHUNK 64
#define NCHUNK 32   // per sequence

// ---------------- fused f32 -> f16 casts (x + weights + interleaved gate weights) ----------------
__global__ __launch_bounds__(256) void cast_all(const float* __restrict__ x,
                                                const float* __restrict__ Wq,
                                                const float* __restrict__ Wk,
                                                const float* __restrict__ Wv,
                                                const float* __restrict__ Wog,
                                                const float* __restrict__ Wig,
                                                const float* __restrict__ Wfg,
                                                const float* __restrict__ Wout,
                                                f16* __restrict__ xf,
                                                f16* __restrict__ wcat,
                                                f16* __restrict__ woutf,
                                                f16* __restrict__ wg16) {
    int i = blockIdx.x * 256 + threadIdx.x;   // float4 index
    if (i >= 5242880 && i < 5251072) {        // gate weights, interleaved dst
        const bool isf = (i >= 5246976);
        const int local = i - (isf ? 5246976 : 5242880);
        const float* src = isf ? Wfg : Wig;
        const int h = local >> 9;
        const int off = (local & 511) * 4;
        float4 v = reinterpret_cast<const float4*>(src)[local];
        f16x4 o = { (f16)v.x, (f16)v.y, (f16)v.z, (f16)v.w };
        *reinterpret_cast<f16x4*>(&wg16[(size_t)(2 * h + (isf ? 1 : 0)) * D_MODEL + off]) = o;
        return;
    }
    const float* src;
    f16* dst;
    int local;
    if (i < 2097152)      { src = x;    dst = xf;                        local = i; }
    else if (i < 2621440) { src = Wq;   dst = wcat;                      local = i - 2097152; }
    else if (i < 3145728) { src = Wk;   dst = wcat + (size_t)2097152;    local = i - 2621440; }
    else if (i < 4194304) { src = Wv;   dst = wcat + (size_t)4194304;    local = i - 3145728; }
    else if (i < 5242880) { src = Wog;  dst = wcat + (size_t)8388608;    local = i - 4194304; }
    else                  { src = Wout; dst = woutf;                     local = i - 5251072; }
    float4 v = reinterpret_cast<const float4*>(src)[local];
    f16x4 o = { (f16)v.x, (f16)v.y, (f16)v.z, (f16)v.w };
    reinterpret_cast<f16x4*>(dst)[local] = o;
}

// ---------------- deep-pipelined GEMM 256x192 for the qkvo projection ----------------
// Epilogue routes: q -> qkvo (scaled), k -> qkvo + kT[bh][dq][s], v -> vT[bh][dv][s] only,
// og -> qkvo. kT/vT get f16x4 stores (4 consecutive s = 4 consecutive rows).
__global__ __launch_bounds__(512, 1) void gemm192(const f16* __restrict__ A,
                                                  const f16* __restrict__ B,
                                                  f16* __restrict__ C,
                                                  f16* __restrict__ kT,
                                                  f16* __restrict__ vT,
                                                  int K, int ldc, float scale) {
    extern __shared__ char lds[];
    const int nt = K >> 6;
    const int tid = threadIdx.x;
    const int w  = tid >> 6;
    const int l  = tid & 63;
    const int wr = w >> 1;
    const int wc = w & 1;
    const int m0 = blockIdx.y * 256;
    const int n0 = blockIdx.x * 192;

    const int r0  = w * 8 + (l >> 3);
    const int csw = ((l & 7) ^ (l >> 3)) * 8;
    const f16* Ab = A + (size_t)(m0 + (r0 >> 5) * 64 + (r0 & 31)) * K + csw;
    const f16* Bb = B + (size_t)(n0 + w * 8 + (l >> 3)) * K + csw;

    const int arow = wr * 32 + (l & 15);
    const int tcol = (l >> 4) * 16;
    const int sx   = (l & 7) << 4;

    f32x4 acc[4][6];
#pragma unroll
    for (int i = 0; i < 4; i++)
#pragma unroll
        for (int j = 0; j < 6; j++) acc[i][j] = (f32x4){0.f, 0.f, 0.f, 0.f};
    f16x8 a[2][2];
    f16x8 b[6][2];

    auto SA = [&](int kt, int ag, int buf) {
        const int kc = (kt < nt ? kt : nt - 1) << 6;
#pragma unroll
        for (int q = 0; q < 2; q++)
            __builtin_amdgcn_global_load_lds(
                (const __attribute__((address_space(1))) void*)(Ab + (size_t)(q * 128 + ag * 32) * K + kc),
                (__attribute__((address_space(3))) void*)(lds + buf * 32768 + (ag * 128 + q * 64 + w * 8) * 128),
                16, 0, 0);
    };
    auto SB1 = [&](int kt, int c, int buf) {
        const int kc = (kt < nt ? kt : nt - 1) << 6;
        __builtin_amdgcn_global_load_lds(
            (const __attribute__((address_space(1))) void*)(Bb + (size_t)(c * 64) * K + kc),
            (__attribute__((address_space(3))) void*)(lds + 65536 + buf * 24576 + (c * 64 + w * 8) * 128),
            16, 0, 0);
    };
    auto LDA = [&](int ag, int buf) {
#pragma unroll
        for (int fr = 0; fr < 2; fr++)
#pragma unroll
            for (int ks = 0; ks < 2; ks++)
                a[fr][ks] = *reinterpret_cast<const f16x8*>(
                    lds + buf * 32768 + (ag * 128 + arow + fr * 16) * 128 + ((ks * 64 + tcol) ^ sx));
    };
    auto LDB = [&](int buf) {
#pragma unroll
        for (int nf = 0; nf < 6; nf++)
#pragma unroll
            for (int ks = 0; ks < 2; ks++)
                b[nf][ks] = *reinterpret_cast<const f16x8*>(
                    lds + 65536 + buf * 24576 + (wc * 96 + nf * 16 + (l & 15)) * 128 + ((ks * 64 + tcol) ^ sx));
    };
    auto MM = [&](int ai) {
#pragma unroll
        for (int fa = 0; fa < 2; fa++)
#pragma unroll
            for (int nf = 0; nf < 6; nf++)
#pragma unroll
                for (int ks = 0; ks < 2; ks++)
                    acc[ai + fa][nf] = __builtin_amdgcn_mfma_f32_16x16x32_f16(
                        a[fa][ks], b[nf][ks], acc[ai + fa][nf], 0, 0, 0);
    };

#define BAR() do { asm volatile("" ::: "memory"); \
                   __builtin_amdgcn_s_barrier(); \
                   asm volatile("" ::: "memory"); } while (0)
#define VM7() asm volatile("s_waitcnt vmcnt(7)" ::: "memory")

    SB1(0, 0, 0); SB1(0, 1, 0); SB1(0, 2, 0); SA(0, 0, 0); SA(0, 1, 0);
    SB1(1, 0, 1); SB1(1, 1, 1); SB1(1, 2, 1); SA(1, 0, 1);
    asm volatile("s_waitcnt vmcnt(5)" ::: "memory");
    BAR();

    for (int kt = 0; kt < nt; kt++) {
        const int cur = kt & 1, nxt = cur ^ 1;
        SA(kt + 1, 1, nxt);
        LDA(0, cur); LDB(cur);
        __builtin_amdgcn_s_setprio(1); MM(0); __builtin_amdgcn_s_setprio(0);
        VM7();
        BAR();
        SB1(kt + 2, 0, cur); SB1(kt + 2, 1, cur); SB1(kt + 2, 2, cur); SA(kt + 2, 0, cur);
        LDA(1, cur);
        __builtin_amdgcn_s_setprio(1); MM(2); __builtin_amdgcn_s_setprio(0);
        VM7();
        BAR();
    }
#undef BAR
#undef VM7

    const int crow = m0 + wr * 64 + (l >> 4) * 4;
    const int ccol = n0 + wc * 96 + (l & 15);
#pragma unroll
    for (int i = 0; i < 4; i++) {
        const int row0 = crow + i * 16;
        const int bb = row0 >> 11;
        const int s0 = row0 & 2047;
#pragma unroll
        for (int j = 0; j < 6; j++) {
            const int col = ccol + j * 16;
            if (col < KOFF) {                         // q (scaled)
#pragma unroll
                for (int r = 0; r < 4; r++)
                    C[(size_t)(row0 + r) * ldc + col] = (f16)(acc[i][j][r] * scale);
            } else if (col < VOFF) {                  // k: natural + kT
                const int dq = col - KOFF;
                f16x4 kv;
#pragma unroll
                for (int r = 0; r < 4; r++) {
                    const f16 v = (f16)acc[i][j][r];
                    C[(size_t)(row0 + r) * ldc + col] = v;
                    kv[r] = v;
                }
                *reinterpret_cast<f16x4*>(
                    &kT[(((size_t)bb * 8 + (dq >> 7)) * 128 + (dq & 127)) * 2048 + s0]) = kv;
            } else if (col < OGOFF) {                 // v: vT only
                const int dv = col - VOFF;
                f16x4 vv;
#pragma unroll
                for (int r = 0; r < 4; r++) vv[r] = (f16)acc[i][j][r];
                *reinterpret_cast<f16x4*>(
                    &vT[(((size_t)bb * 8 + (dv >> 8)) * 256 + (dv & 255)) * 2048 + s0]) = vv;
            } else {                                  // og
#pragma unroll
                for (int r = 0; r < 4; r++)
                    C[(size_t)(row0 + r) * ldc + col] = (f16)acc[i][j][r];
            }
        }
    }
}

// ---------------- deep-pipelined GEMM 256x128 (proven R12 version, GEMM2) ----------------
template <typename OT>
__global__ __launch_bounds__(512, 1) void gemm256(const f16* __restrict__ A,
                                                  const f16* __restrict__ B,
                                                  OT* __restrict__ C,
                                                  int K, int ldc,
                                                  int scale_cols, float scale) {
    extern __shared__ char lds[];
    const int nt = K >> 6;
    const int tid = threadIdx.x;
    const int w  = tid >> 6;
    const int l  = tid & 63;
    const int wr = w >> 1;
    const int wc = w & 1;
    const int m0 = blockIdx.y * 256;
    const int n0 = blockIdx.x * 128;

    const int r0  = w * 8 + (l >> 3);
    const int csw = ((l & 7) ^ (l >> 3)) * 8;
    const f16* Ab = A + (size_t)(m0 + (r0 >> 5) * 64 + (r0 & 31)) * K + csw;
    const f16* Bb = B + (size_t)(n0 + (r0 >> 5) * 64 + (r0 & 31)) * K + csw;

    const int arow = wr * 32 + (l & 15);
    const int brow = wc * 32 + (l & 15);
    const int tcol = (l >> 4) * 16;
    const int sx   = (l & 7) << 4;

    f32x4 acc[4][4];
#pragma unroll
    for (int i = 0; i < 4; i++)
#pragma unroll
        for (int j = 0; j < 4; j++) acc[i][j] = (f32x4){0.f, 0.f, 0.f, 0.f};
    f16x8 a[2][2];
    f16x8 b[2][2][2];

    auto SA = [&](int kt, int ag, int buf) {
        const int kc = (kt < nt ? kt : nt - 1) << 6;
#pragma unroll
        for (int q = 0; q < 2; q++)
            __builtin_amdgcn_global_load_lds(
                (const __attribute__((address_space(1))) void*)(Ab + (size_t)(q * 128 + ag * 32) * K + kc),
                (__attribute__((address_space(3))) void*)(lds + buf * 32768 + (ag * 128 + q * 64 + w * 8) * 128),
                16, 0, 0);
    };
    auto SB = [&](int kt, int bg, int buf) {
        const int kc = (kt < nt ? kt : nt - 1) << 6;
        __builtin_amdgcn_global_load_lds(
            (const __attribute__((address_space(1))) void*)(Bb + (size_t)(bg * 32) * K + kc),
            (__attribute__((address_space(3))) void*)(lds + 65536 + buf * 16384 + (bg * 64 + w * 8) * 128),
            16, 0, 0);
    };
    auto LDA = [&](int ag, int buf) {
#pragma unroll
        for (int fr = 0; fr < 2; fr++)
#pragma unroll
            for (int ks = 0; ks < 2; ks++)
                a[fr][ks] = *reinterpret_cast<const f16x8*>(
                    lds + buf * 32768 + (ag * 128 + arow + fr * 16) * 128 + ((ks * 64 + tcol) ^ sx));
    };
    auto LDB = [&](int bg, int buf) {
#pragma unroll
        for (int fr = 0; fr < 2; fr++)
#pragma unroll
            for (int ks = 0; ks < 2; ks++)
                b[bg][fr][ks] = *reinterpret_cast<const f16x8*>(
                    lds + 65536 + buf * 16384 + (bg * 64 + brow + fr * 16) * 128 + ((ks * 64 + tcol) ^ sx));
    };
    auto MM = [&](int ai, int bg) {
#pragma unroll
        for (int fa = 0; fa < 2; fa++)
#pragma unroll
            for (int fb = 0; fb < 2; fb++)
#pragma unroll
                for (int ks = 0; ks < 2; ks++)
                    acc[ai + fa][bg * 2 + fb] = __builtin_amdgcn_mfma_f32_16x16x32_f16(
                        a[fa][ks], b[bg][fb][ks], acc[ai + fa][bg * 2 + fb], 0, 0, 0);
    };

#define BAR() do { asm volatile("" ::: "memory"); \
                   __builtin_amdgcn_s_barrier(); \
                   asm volatile("" ::: "memory"); } while (0)
#define VM6() asm volatile("s_waitcnt vmcnt(6)" ::: "memory")

    SB(0, 0, 0); SB(0, 1, 0); SA(0, 0, 0); SA(0, 1, 0);
    SB(1, 0, 1); SB(1, 1, 1); SA(1, 0, 1);
    asm volatile("s_waitcnt vmcnt(4)" ::: "memory");
    BAR();

    for (int kt = 0; kt < nt; kt++) {
        const int cur = kt & 1, nxt = cur ^ 1;
        SA(kt + 1, 1, nxt);
        LDA(0, cur); LDB(0, cur); LDB(1, cur);
        __builtin_amdgcn_s_setprio(1); MM(0, 0); MM(0, 1); __builtin_amdgcn_s_setprio(0);
        VM6();
        BAR();
        SB(kt + 2, 0, cur); SB(kt + 2, 1, cur); SA(kt + 2, 0, cur);
        LDA(1, cur);
        __builtin_amdgcn_s_setprio(1); MM(2, 0); MM(2, 1); __builtin_amdgcn_s_setprio(0);
        VM6();
        BAR();
    }
#undef BAR
#undef VM6

    const int crow = m0 + wr * 64 + (l >> 4) * 4;
    const int ccol = n0 + wc * 64 + (l & 15);
#pragma unroll
    for (int i = 0; i < 4; i++) {
#pragma unroll
        for (int j = 0; j < 4; j++) {
            const int col = ccol + j * 16;
            const float sc = (col < scale_cols) ? scale : 1.f;
#pragma unroll
            for (int r = 0; r < 4; r++)
                C[(size_t)(crow + i * 16 + r) * ldc + col] = (OT)(acc[i][j][r] * sc);
        }
    }
}

// ---------------- gate projection ----------------
__global__ __launch_bounds__(256) void gate_proj(const f16* __restrict__ xf,
                                                 const f16* __restrict__ wg16,
                                                 const float* __restrict__ big,
                                                 const float* __restrict__ bfg,
                                                 float* __restrict__ gates) {
    __shared__ float red[4][16][16];
    const int tid = threadIdx.x, w = tid >> 6, l = tid & 63;
    const int r0 = blockIdx.x * 16;
    const int kbase = w * 512 + (l >> 4) * 8;
    const f16* ap = xf + (size_t)(r0 + (l & 15)) * D_MODEL + kbase;
    const f16* bp = wg16 + (size_t)(l & 15) * D_MODEL + kbase;
    f32x4 acc = (f32x4){0.f, 0.f, 0.f, 0.f};
#pragma unroll
    for (int k0 = 0; k0 < 512; k0 += 32) {
        f16x8 af = *reinterpret_cast<const f16x8*>(ap + k0);
        f16x8 bf = *reinterpret_cast<const f16x8*>(bp + k0);
        acc = __builtin_amdgcn_mfma_f32_16x16x32_f16(af, bf, acc, 0, 0, 0);
    }
#pragma unroll
    for (int r = 0; r < 4; r++) red[w][(l >> 4) * 4 + r][l & 15] = acc[r];
    __syncthreads();
    const int row = tid >> 4, col = tid & 15;
    const float bias = (col & 1) ? bfg[col >> 1] : big[col >> 1];
    const float total = red[0][row][col] + red[1][row][col]
                      + red[2][row][col] + red[3][row][col] + bias;
    gates[(size_t)(r0 + row) * 16 + col] = total;
}

// ---------------- gate scan ----------------
__global__ __launch_bounds__(256) void gate_scan(const float* __restrict__ gates,
                                                 float4* __restrict__ gs4,
                                                 float2* __restrict__ gchunk,
                                                 float* __restrict__ mf) {
    const int bh = blockIdx.x;
    const int b = bh >> 3, h = bh & 7;
    const int tid = threadIdx.x;
    __shared__ float2 sif[S_LEN];
    __shared__ float2 comp[NCHUNK];
    for (int t = tid; t < S_LEN; t += 256) {
        const float2 pre = *reinterpret_cast<const float2*>(
            &gates[((size_t)b * S_LEN + t) * 16 + h * 2]);
        const float ic = 15.f * tanhf(pre.x * (1.f / 15.f));
        const float fc = 15.f * tanhf(pre.y * (1.f / 15.f));
        const float flog = fminf(fc, 0.f) - log1pf(expf(-fabsf(fc)));
        sif[t] = make_float2(ic, flog);
    }
    __syncthreads();
    if (tid < NCHUNK) {
        float bsum = 0.f, r = -1e30f;
        for (int s = 0; s < CHUNK; s++) {
            const float2 g = sif[tid * CHUNK + s];
            bsum += g.y;
            r = fmaxf(r, g.x - bsum);
        }
        comp[tid] = make_float2(bsum, r);
    }
    __syncthreads();
    if (tid < NCHUNK) {
        float m0 = 0.f;
        for (int c = 0; c < tid; c++) m0 = comp[c].x + fmaxf(m0, comp[c].y);
        float4* out = gs4 + (size_t)bh * S_LEN + tid * CHUNK;
        float bsum = 0.f, r = -1e30f;
        float mlast = 0.f, Alast = 0.f, alast = 0.f;
        for (int s = 0; s < CHUNK; s++) {
            const float2 g = sif[tid * CHUNK + s];
            bsum += g.y;
            const float uu = g.x - bsum;
            r = fmaxf(r, uu);
            const float mx = fmaxf(m0, r);
            const float mt = bsum + mx;
            const float At = -mx;
            const float al = expf(m0 + At);
            out[s] = make_float4(uu, At, al, expf(-mt));
            if (s == CHUNK - 1) { mlast = mt; Alast = At; alast = al; }
        }
        gchunk[bh * NCHUNK + tid] = make_float2(alast, Alast);
        if (tid == NCHUNK - 1) mf[bh] = mlast;
    }
}

// ---------------- phase A: intra attention + chunk summaries; h_intra -> hbuf ----------------
// Transposes come pre-made from GEMM1 (kT, vT): all staging is b128.
__global__ __launch_bounds__(256) void phaseA(const f16* __restrict__ qkvo,
                                              const f16* __restrict__ kT,
                                              const f16* __restrict__ vT,
                                              const float4* __restrict__ gs4,
                                              float* __restrict__ qn_intra,
                                              f16* __restrict__ Ubuf,
                                              f16* __restrict__ hbuf,
                                              float* __restrict__ UnB) {
    __shared__ f16 Kn[64][136];
    __shared__ f16 KgT[128][72];
    __shared__ f16 VT[256][72];     // reused as hs[64][260] after U
    __shared__ float u_s[64], A_t[64], gamv[64];
    __shared__ float qnp[4][64];
    f16 (*Pl)[72] = reinterpret_cast<f16(*)[72]>(&Kn[0][0]);
    f16* hs = &VT[0][0];

    const int bid = blockIdx.x;
    const int bh = bid >> 5, ck = bid & 31;
    const int b = bh >> 3, h = bh & 7;
    const int tid = threadIdx.x;
    const int w = tid >> 6, l = tid & 63;

    const size_t rowbase = (size_t)b * S_LEN + ck * CHUNK;

    if (tid < 64) {
        float4 g = gs4[(size_t)bh * S_LEN + ck * CHUNK + tid];
        u_s[tid] = g.x; A_t[tid] = g.y;
    }
    const int sK = tid & 63, quad = tid >> 6;
    // stage Kn (natural K rows, b128)
    {
        const f16* kp = qkvo + (rowbase + sK) * NCOL + KOFF + h * 128 + quad * 32;
#pragma unroll
        for (int i = 0; i < 4; i++)
            *reinterpret_cast<f16x8*>(&Kn[sK][quad * 32 + i * 8]) =
                *reinterpret_cast<const f16x8*>(kp + i * 8);
    }
    // stage VT from vT (coalesced rows; chunk-rotated LDS writes to spread banks)
    {
        const f16* vp = vT + ((size_t)bh * 256 + tid) * 2048 + ck * CHUNK;
#pragma unroll
        for (int i = 0; i < 8; i++) {
            const int c = (i + (tid >> 3)) & 7;
            *reinterpret_cast<f16x8*>(&VT[tid][c * 8]) =
                *reinterpret_cast<const f16x8*>(vp + c * 8);
        }
    }
    __syncthreads();
    if (tid < 64) gamv[tid] = __expf(u_s[tid] + A_t[63]);
    // S^T mfma: A = Kn rows, B = Q from global
    f16x8 af[4];
#pragma unroll
    for (int kk = 0; kk < 4; kk++)
        af[kk] = *reinterpret_cast<const f16x8*>(&Kn[w * 16 + (l & 15)][kk * 32 + (l >> 4) * 8]);
    f32x4 st[4];
#pragma unroll
    for (int ct = 0; ct < 4; ct++) {
        st[ct] = (f32x4){0.f, 0.f, 0.f, 0.f};
#pragma unroll
        for (int kk = 0; kk < 4; kk++) {
            const f16* qp = qkvo + (rowbase + ct * 16 + (l & 15)) * NCOL + QOFF + h * 128 + kk * 32 + (l >> 4) * 8;
            f16x8 bf = *reinterpret_cast<const f16x8*>(qp);
            st[ct] = __builtin_amdgcn_mfma_f32_16x16x32_f16(af[kk], bf, st[ct], 0, 0, 0);
        }
    }
    __syncthreads();   // Kn dead -> Pl alias safe; gamv visible
    // P-weights/mask -> Pl + qn partials
#pragma unroll
    for (int ct = 0; ct < 4; ct++) {
        const int tloc = ct * 16 + (l & 15);
        const float At = A_t[tloc];
        float part = 0.f;
        f16x4 pk;
#pragma unroll
        for (int i = 0; i < 4; i++) {
            const int sloc = w * 16 + (l >> 4) * 4 + i;
            const float val = (sloc <= tloc) ? st[ct][i] * __expf(At + u_s[sloc]) : 0.f;
            part += val;
            pk[i] = (f16)val;
        }
        part += __shfl_xor(part, 16);
        part += __shfl_xor(part, 32);
        if ((l >> 4) == 0) qnp[w][tloc] = part;
        *reinterpret_cast<f16x4*>(&Pl[tloc][w * 16 + (l >> 4) * 4]) = pk;
    }
    // stage KgT from kT with vectorized gamma scale (b128 in/out)
    {
        const int dq = tid >> 1, half2 = tid & 1;
        const f16* kp2 = kT + ((size_t)bh * 128 + dq) * 2048 + ck * CHUNK + half2 * 32;
        const float* gp = &gamv[half2 * 32];
#pragma unroll
        for (int i = 0; i < 4; i++) {
            f16x8 kv = *reinterpret_cast<const f16x8*>(kp2 + i * 8);
            f16x8 o;
#pragma unroll
            for (int e = 0; e < 8; e++) o[e] = (f16)(gp[i * 8 + e] * (float)kv[e]);
            *reinterpret_cast<f16x8*>(&KgT[dq][half2 * 32 + i * 8]) = o;
        }
    }
    __syncthreads();
    if (tid < 64)
        qn_intra[(size_t)bh * S_LEN + ck * CHUNK + tid] =
            qnp[0][tid] + qnp[1][tid] + qnp[2][tid] + qnp[3][tid];
    // PV: accs in registers
    f32x4 hacc[16];
    {
        f16x8 pa[2];
#pragma unroll
        for (int kk = 0; kk < 2; kk++)
            pa[kk] = *reinterpret_cast<const f16x8*>(&Pl[w * 16 + (l & 15)][kk * 32 + (l >> 4) * 8]);
#pragma unroll
        for (int vt = 0; vt < 16; vt++) {
            hacc[vt] = (f32x4){0.f, 0.f, 0.f, 0.f};
#pragma unroll
            for (int kk = 0; kk < 2; kk++) {
                f16x8 vb = *reinterpret_cast<const f16x8*>(&VT[vt * 16 + (l & 15)][kk * 32 + (l >> 4) * 8]);
                hacc[vt] = __builtin_amdgcn_mfma_f32_16x16x32_f16(pa[kk], vb, hacc[vt], 0, 0, 0);
            }
        }
    }
    // U (chunk summary, stored [dv][dq])
#pragma unroll
    for (int q = 0; q < 4; q++) {
        const int dvt = w * 4 + q;
        f16x8 vb[2];
#pragma unroll
        for (int kk = 0; kk < 2; kk++)
            vb[kk] = *reinterpret_cast<const f16x8*>(&VT[dvt * 16 + (l & 15)][kk * 32 + (l >> 4) * 8]);
#pragma unroll
        for (int dqt = 0; dqt < 8; dqt++) {
            f32x4 acc = (f32x4){0.f, 0.f, 0.f, 0.f};
#pragma unroll
            for (int kk = 0; kk < 2; kk++) {
                f16x8 ka = *reinterpret_cast<const f16x8*>(&KgT[dqt * 16 + (l & 15)][kk * 32 + (l >> 4) * 8]);
                acc = __builtin_amdgcn_mfma_f32_16x16x32_f16(ka, vb[kk], acc, 0, 0, 0);
            }
            f16x4 uk;
#pragma unroll
            for (int i = 0; i < 4; i++) uk[i] = (f16)acc[i];
            const size_t addr = (((size_t)bh * NCHUNK + ck) * 256 + dvt * 16 + (l & 15)) * 128
                              + dqt * 16 + (l >> 4) * 4;
            *reinterpret_cast<f16x4*>(&Ubuf[addr]) = uk;
        }
    }
    // Un row-sums
    {
        const int dq = tid >> 1, half2 = tid & 1;
        float sum = 0.f;
#pragma unroll
        for (int i = 0; i < 4; i++) {
            f16x8 kv = *reinterpret_cast<const f16x8*>(&KgT[dq][half2 * 32 + i * 8]);
#pragma unroll
            for (int e = 0; e < 8; e++) sum += (float)kv[e];
        }
        sum += __shfl_xor(sum, 1);
        if (half2 == 0) UnB[((size_t)bh * NCHUNK + ck) * 128 + dq] = sum;
    }
    // transpose h_intra through LDS (VT dead) -> coalesced hbuf write
    __syncthreads();
#pragma unroll
    for (int vt = 0; vt < 16; vt++)
#pragma unroll
        for (int i = 0; i < 4; i++)
            hs[(w * 16 + (l >> 4) * 4 + i) * 260 + vt * 16 + (l & 15)] = (f16)hacc[vt][i];
    __syncthreads();
#pragma unroll
    for (int k = 0; k < 8; k++) {
        const int id = tid + k * 256;
        const int row = id >> 5, c8 = id & 31;
        f16x8 v = *reinterpret_cast<const f16x8*>(&hs[row * 260 + c8 * 8]);
        *reinterpret_cast<f16x8*>(&hbuf[(rowbase + row) * D_MODEL + h * 256 + c8 * 8]) = v;
    }
}

// ---------------- phase B: inter-chunk C and n recurrences; updates hbuf in place ----------------
__global__ __launch_bounds__(256) void phaseB(const f16* __restrict__ qkvo,
                                              const f16* __restrict__ Ubuf,
                                              const float4* __restrict__ gs4,
                                              const float2* __restrict__ gchunk,
                                              const float* __restrict__ qn_intra,
                                              const float* __restrict__ UnB,
                                              f16* __restrict__ hbuf,
                                              float* __restrict__ Cf,
                                              float* __restrict__ nf) {
    const int bid = blockIdx.x;
    const int bh = bid >> 4, vt = bid & 15;
    const int b = bh >> 3, h = bh & 7;
    const int tid = threadIdx.x, w = tid >> 6, l = tid & 63;
    const int dv = vt * 16 + (l & 15);

    float c[4][8];
    float nn[4][8];
#pragma unroll
    for (int kk = 0; kk < 4; kk++)
#pragma unroll
        for (int j = 0; j < 8; j++) { c[kk][j] = 0.f; nn[kk][j] = 0.f; }

    for (int ck = 0; ck < NCHUNK; ck++) {
        f16x8 uf[4];
        const f16* ub = Ubuf + (((size_t)bh * NCHUNK + ck) * 256 + dv) * 128 + (l >> 4) * 8;
#pragma unroll
        for (int kk = 0; kk < 4; kk++) uf[kk] = *reinterpret_cast<const f16x8*>(ub + kk * 32);
        float un[4][8];
        const float* unp = UnB + ((size_t)bh * NCHUNK + ck) * 128 + (l >> 4) * 8;
#pragma unroll
        for (int kk = 0; kk < 4; kk++) {
            const float4 u0 = *reinterpret_cast<const float4*>(unp + kk * 32);
            const float4 u1 = *reinterpret_cast<const float4*>(unp + kk * 32 + 4);
            un[kk][0] = u0.x; un[kk][1] = u0.y; un[kk][2] = u0.z; un[kk][3] = u0.w;
            un[kk][4] = u1.x; un[kk][5] = u1.y; un[kk][6] = u1.z; un[kk][7] = u1.w;
        }
        const int t0 = ck * CHUNK + w * 16;
        f16x8 af[4];
        const f16* qp = qkvo + ((size_t)b * S_LEN + t0 + (l & 15)) * NCOL + QOFF + h * 128 + (l >> 4) * 8;
#pragma unroll
        for (int kk = 0; kk < 4; kk++) af[kk] = *reinterpret_cast<const f16x8*>(qp + kk * 32);
        f16x8 cf[4], cfn[4];
#pragma unroll
        for (int kk = 0; kk < 4; kk++)
#pragma unroll
            for (int j = 0; j < 8; j++) { cf[kk][j] = (f16)c[kk][j]; cfn[kk][j] = (f16)nn[kk][j]; }
        f32x4 H  = (f32x4){0.f, 0.f, 0.f, 0.f};
        f32x4 Hn = (f32x4){0.f, 0.f, 0.f, 0.f};
#pragma unroll
        for (int kk = 0; kk < 4; kk++) {
            H  = __builtin_amdgcn_mfma_f32_16x16x32_f16(af[kk], cf[kk],  H,  0, 0, 0);
            Hn = __builtin_amdgcn_mfma_f32_16x16x32_f16(af[kk], cfn[kk], Hn, 0, 0, 0);
        }
        const int tt = t0 + (l >> 4) * 4;
        const float4 qnI = *reinterpret_cast<const float4*>(&qn_intra[(size_t)bh * S_LEN + tt]);
        const float qni[4] = {qnI.x, qnI.y, qnI.z, qnI.w};
#pragma unroll
        for (int i = 0; i < 4; i++) {
            const float4 g = gs4[(size_t)bh * S_LEN + tt + i];
            const float al = g.z;
            const float qn = qni[i] + al * Hn[i];
            const float rd = 1.f / (fmaxf(fabsf(qn), g.w) + 1e-6f);
            const size_t hidx = ((size_t)b * S_LEN + tt + i) * D_MODEL + h * 256 + dv;
            const float hval = ((float)hbuf[hidx] + al * H[i]) * rd;
            hbuf[hidx] = (f16)hval;
        }
        const float F = gchunk[bh * NCHUNK + ck].x;
#pragma unroll
        for (int kk = 0; kk < 4; kk++)
#pragma unroll
            for (int j = 0; j < 8; j++) {
                c[kk][j]  = fmaf(F, c[kk][j],  (float)uf[kk][j]);
                nn[kk][j] = fmaf(F, nn[kk][j], un[kk][j]);
            }
    }
    if (w == 0) {
#pragma unroll
        for (int kk = 0; kk < 4; kk++)
#pragma unroll
            for (int j = 0; j < 8; j++) {
                const int dq = kk * 32 + (l >> 4) * 8 + j;
                Cf[((size_t)bh * 128 + dq) * 256 + dv] = c[kk][j];
            }
        if (vt == 0 && (l & 15) == 0) {
#pragma unroll
            for (int kk = 0; kk < 4; kk++)
#pragma unroll
                for (int j = 0; j < 8; j++) {
                    const int dq = kk * 32 + (l >> 4) * 8 + j;
                    nf[(size_t)bh * 128 + dq] = nn[kk][j];
                }
        }
    }
}

// ---------------- per-head layernorm * gamma * sigmoid(og), f16 in/out ----------------
__global__ __launch_bounds__(256) void norm_kernel(const f16* __restrict__ hbuf,
                                                   const f16* __restrict__ qkvo,
                                                   const float* __restrict__ gamma,
                                                   f16* __restrict__ hout) {
    const int row = blockIdx.x;
    const int tid = threadIdx.x;
    const int g = tid >> 5;
    const int l = tid & 31;
    const f16* hrow = hbuf + (size_t)row * D_MODEL + g * 256 + l * 8;
    f16x8 hv8 = *reinterpret_cast<const f16x8*>(hrow);
    float hv[8];
#pragma unroll
    for (int e = 0; e < 8; e++) hv[e] = (float)hv8[e];
    float s = 0.f, s2 = 0.f;
#pragma unroll
    for (int e = 0; e < 8; e++) { s += hv[e]; s2 += hv[e] * hv[e]; }
#pragma unroll
    for (int off = 1; off < 32; off <<= 1) {
        s  += __shfl_xor(s, off);
        s2 += __shfl_xor(s2, off);
    }
    const float mu  = s * (1.f / 256.f);
    const float var = s2 * (1.f / 256.f) - mu * mu;
    const float rs  = rsqrtf(var + 1e-6f);
    const f16* ogr = qkvo + (size_t)row * NCOL + OGOFF + g * 256 + l * 8;
    f16x8 og8 = *reinterpret_cast<const f16x8*>(ogr);
    const float* gam = gamma + g * 256 + l * 8;
    f16x8 o;
#pragma unroll
    for (int e = 0; e < 8; e++) {
        const float og  = (float)og8[e];
        const float sig = __builtin_amdgcn_rcpf(1.f + __expf(-og));
        const float hn  = (hv[e] - mu) * rs * gam[e];
        o[e] = (f16)(sig * hn);
    }
    *reinterpret_cast<f16x8*>(&hout[(size_t)row * D_MODEL + g * 256 + l * 8]) = o;
}

// ---------------- launch ----------------
extern "C" void kernel_launch(void* const* d_in, const int* in_sizes, int n_in,
                              void* d_out, int out_size, void* d_ws, size_t ws_size,
                              hipStream_t stream) {
    (void)in_sizes; (void)n_in; (void)out_size; (void)ws_size;
    const float* x     = (const float*)d_in[0];
    const float* Wq    = (const float*)d_in[1];
    const float* Wk    = (const float*)d_in[2];
    const float* Wv    = (const float*)d_in[3];
    const float* Wog   = (const float*)d_in[4];
    const float* Wig   = (const float*)d_in[5];
    const float* big   = (const float*)d_in[6];
    const float* Wfg   = (const float*)d_in[7];
    const float* bfg   = (const float*)d_in[8];
    const float* gamma = (const float*)d_in[9];
    const float* Wout  = (const float*)d_in[10];

    char* ws = (char*)d_ws;
    size_t off = 0;
    f16*    xf     = (f16*)(ws + off);    off += (size_t)NROWS * D_MODEL * 2;
    f16*    wcat   = (f16*)(ws + off);    off += (size_t)NCOL * D_MODEL * 2;
    f16*    woutf  = (f16*)(ws + off);    off += (size_t)D_MODEL * D_MODEL * 2;
    f16*    wg16   = (f16*)(ws + off);    off += (size_t)16 * D_MODEL * 2;
    f16*    qkvo   = (f16*)(ws + off);    off += (size_t)NROWS * NCOL * 2;
    f16*    kT     = (f16*)(ws + off);    off += (size_t)16 * 128 * S_LEN * 2;
    f16*    vT     = (f16*)(ws + off);    off += (size_t)16 * 256 * S_LEN * 2;
    float*  gates  = (float*)(ws + off);  off += (size_t)NROWS * 16 * 4;
    float4* gs4    = (float4*)(ws + off); off += (size_t)16 * S_LEN * 16;
    float2* gchunk = (float2*)(ws + off); off += (size_t)16 * NCHUNK * 8;
    float*  qn_i   = (float*)(ws + off);  off += (size_t)16 * S_LEN * 4;
    float*  UnB    = (float*)(ws + off);  off += (size_t)16 * NCHUNK * 128 * 4;
    f16*    Ubuf   = (f16*)(ws + off);    off += (size_t)16 * NCHUNK * 256 * 128 * 2;
    f16*    hbuf   = (f16*)(ws + off);    off += (size_t)NROWS * D_MODEL * 2;
    f16*    houtf  = xf;  // xf dead after GEMM1

    float* y  = (float*)d_out;
    float* Cf = y + (size_t)NROWS * D_MODEL;
    float* nf = Cf + (size_t)16 * 128 * 256;
    float* mf = nf + (size_t)16 * 128;

    // fused casts
    cast_all<<<24608, 256, 0, stream>>>(x, Wq, Wk, Wv, Wog, Wig, Wfg, Wout,
                                        xf, wcat, woutf, wg16);

    // gate projection + chunk decomposition
    gate_proj<<<NROWS / 16, 256, 0, stream>>>(xf, wg16, big, bfg, gates);
    gate_scan<<<16, 256, 0, stream>>>(gates, gs4, gchunk, mf);

    // fused qkvo projection; writes q/k/og natural + kT/vT transposed
    gemm192<<<dim3(NCOL / 192, NROWS / 256), 512, 114688, stream>>>(
        xf, wcat, qkvo, kT, vT, D_MODEL, NCOL, 0.08838834764831845f);

    // chunkwise mLSTM
    phaseA<<<512, 256, 0, stream>>>(qkvo, kT, vT, gs4, qn_i, Ubuf, hbuf, UnB);
    phaseB<<<256, 256, 0, stream>>>(qkvo, Ubuf, gs4, gchunk, qn_i, UnB, hbuf, Cf, nf);

    // multihead norm + output gate
    norm_kernel<<<NROWS, 256, 0, stream>>>(hbuf, qkvo, gamma, houtf);

    // y = h_out @ Wout^T
    gemm256<float><<<dim3(D_MODEL / 128, NROWS / 256), 512, 98304, stream>>>(
        houtf, woutf, y, D_MODEL, D_MODEL, 0, 1.f);
}

// Round 16
// 286.620 us; speedup vs baseline: 1.0327x; 1.0327x over previous
//
#include <hip/hip_runtime.h>

typedef _Float16 f16;
typedef f16 f16x8 __attribute__((ext_vector_type(8)));
typedef f16 f16x4 __attribute__((ext_vector_type(4)));
typedef float f32x4 __attribute__((ext_vector_type(4)));

#define S_LEN 2048
#define D_MODEL 2048
#define NHEADS 8
#define DQ 128
#define DV 256
#define NCOL 6144   // q(1024) | k(1024) | v(2048) | og(2048)
#define QOFF 0
#define KOFF 1024
#define VOFF 2048
#define OGOFF 4096
#define NROWS 4096  // B*S
#define CHUNK 64
#define NCHUNK 32   // per sequence

// ---------------- fused f32 -> f16 casts (x + weights + interleaved gate weights) ----------------
__global__ __launch_bounds__(256) void cast_all(const float* __restrict__ x,
                                                const float* __restrict__ Wq,
                                                const float* __restrict__ Wk,
                                                const float* __restrict__ Wv,
                                                const float* __restrict__ Wog,
                                                const float* __restrict__ Wig,
                                                const float* __restrict__ Wfg,
                                                const float* __restrict__ Wout,
                                                f16* __restrict__ xf,
                                                f16* __restrict__ wcat,
                                                f16* __restrict__ woutf,
                                                f16* __restrict__ wg16) {
    int i = blockIdx.x * 256 + threadIdx.x;   // float4 index
    if (i >= 5242880 && i < 5251072) {        // gate weights, interleaved dst
        const bool isf = (i >= 5246976);
        const int local = i - (isf ? 5246976 : 5242880);
        const float* src = isf ? Wfg : Wig;
        const int h = local >> 9;
        const int off = (local & 511) * 4;
        float4 v = reinterpret_cast<const float4*>(src)[local];
        f16x4 o = { (f16)v.x, (f16)v.y, (f16)v.z, (f16)v.w };
        *reinterpret_cast<f16x4*>(&wg16[(size_t)(2 * h + (isf ? 1 : 0)) * D_MODEL + off]) = o;
        return;
    }
    const float* src;
    f16* dst;
    int local;
    if (i < 2097152)      { src = x;    dst = xf;                        local = i; }
    else if (i < 2621440) { src = Wq;   dst = wcat;                      local = i - 2097152; }
    else if (i < 3145728) { src = Wk;   dst = wcat + (size_t)2097152;    local = i - 2621440; }
    else if (i < 4194304) { src = Wv;   dst = wcat + (size_t)4194304;    local = i - 3145728; }
    else if (i < 5242880) { src = Wog;  dst = wcat + (size_t)8388608;    local = i - 4194304; }
    else                  { src = Wout; dst = woutf;                     local = i - 5251072; }
    float4 v = reinterpret_cast<const float4*>(src)[local];
    f16x4 o = { (f16)v.x, (f16)v.y, (f16)v.z, (f16)v.w };
    reinterpret_cast<f16x4*>(dst)[local] = o;
}

// ---------------- deep-pipelined GEMM 256x192: C = A @ B^T ----------------
// BK=64, 8 waves (4M x 2N, per-wave 64x96). LDS: A 2x32KB, B 2x24KB = 112KB.
// 2 phases/K-tile, 24 MFMA/phase, uniform vmcnt(7), T2 swizzle, setprio.
// grid.x must be a multiple of 8.
template <typename OT>
__global__ __launch_bounds__(512, 1) void gemm192(const f16* __restrict__ A,
                                                  const f16* __restrict__ B,
                                                  OT* __restrict__ C,
                                                  int K, int ldc,
                                                  int scale_cols, float scale) {
    extern __shared__ char lds[];
    const int nt = K >> 6;
    const int tid = threadIdx.x;
    const int w  = tid >> 6;
    const int l  = tid & 63;
    const int wr = w >> 1;          // 0..3 : 64-row M window
    const int wc = w & 1;           // 0..1 : 96-col N window
    const int m0 = blockIdx.y * 256;
    const int n0 = blockIdx.x * 192;

    const int r0  = w * 8 + (l >> 3);
    const int csw = ((l & 7) ^ (l >> 3)) * 8;
    const f16* Ab = A + (size_t)(m0 + (r0 >> 5) * 64 + (r0 & 31)) * K + csw;
    const f16* Bb = B + (size_t)(n0 + w * 8 + (l >> 3)) * K + csw;

    const int arow = wr * 32 + (l & 15);
    const int tcol = (l >> 4) * 16;
    const int sx   = (l & 7) << 4;

    f32x4 acc[4][6];
#pragma unroll
    for (int i = 0; i < 4; i++)
#pragma unroll
        for (int j = 0; j < 6; j++) acc[i][j] = (f32x4){0.f, 0.f, 0.f, 0.f};
    f16x8 a[2][2];
    f16x8 b[6][2];

    auto SA = [&](int kt, int ag, int buf) {    // 2 DMA calls
        const int kc = (kt < nt ? kt : nt - 1) << 6;
#pragma unroll
        for (int q = 0; q < 2; q++)
            __builtin_amdgcn_global_load_lds(
                (const __attribute__((address_space(1))) void*)(Ab + (size_t)(q * 128 + ag * 32) * K + kc),
                (__attribute__((address_space(3))) void*)(lds + buf * 32768 + (ag * 128 + q * 64 + w * 8) * 128),
                16, 0, 0);
    };
    auto SB1 = [&](int kt, int c, int buf) {    // 1 DMA call: B rows c*64..+63
        const int kc = (kt < nt ? kt : nt - 1) << 6;
        __builtin_amdgcn_global_load_lds(
            (const __attribute__((address_space(1))) void*)(Bb + (size_t)(c * 64) * K + kc),
            (__attribute__((address_space(3))) void*)(lds + 65536 + buf * 24576 + (c * 64 + w * 8) * 128),
            16, 0, 0);
    };
    auto LDA = [&](int ag, int buf) {
#pragma unroll
        for (int fr = 0; fr < 2; fr++)
#pragma unroll
            for (int ks = 0; ks < 2; ks++)
                a[fr][ks] = *reinterpret_cast<const f16x8*>(
                    lds + buf * 32768 + (ag * 128 + arow + fr * 16) * 128 + ((ks * 64 + tcol) ^ sx));
    };
    auto LDB = [&](int buf) {
#pragma unroll
        for (int nf = 0; nf < 6; nf++)
#pragma unroll
            for (int ks = 0; ks < 2; ks++)
                b[nf][ks] = *reinterpret_cast<const f16x8*>(
                    lds + 65536 + buf * 24576 + (wc * 96 + nf * 16 + (l & 15)) * 128 + ((ks * 64 + tcol) ^ sx));
    };
    auto MM = [&](int ai) {
#pragma unroll
        for (int fa = 0; fa < 2; fa++)
#pragma unroll
            for (int nf = 0; nf < 6; nf++)
#pragma unroll
                for (int ks = 0; ks < 2; ks++)
                    acc[ai + fa][nf] = __builtin_amdgcn_mfma_f32_16x16x32_f16(
                        a[fa][ks], b[nf][ks], acc[ai + fa][nf], 0, 0, 0);
    };

#define BAR() do { asm volatile("" ::: "memory"); \
                   __builtin_amdgcn_s_barrier(); \
                   asm volatile("" ::: "memory"); } while (0)
#define VM7() asm volatile("s_waitcnt vmcnt(7)" ::: "memory")

    // prologue: t0 full (7) + t1 part (5)
    SB1(0, 0, 0); SB1(0, 1, 0); SB1(0, 2, 0); SA(0, 0, 0); SA(0, 1, 0);
    SB1(1, 0, 1); SB1(1, 1, 1); SB1(1, 2, 1); SA(1, 0, 1);
    asm volatile("s_waitcnt vmcnt(5)" ::: "memory");   // t0 complete
    BAR();

    for (int kt = 0; kt < nt; kt++) {
        const int cur = kt & 1, nxt = cur ^ 1;
        // ph0: (a0 x b0..5)
        SA(kt + 1, 1, nxt);
        LDA(0, cur); LDB(cur);
        __builtin_amdgcn_s_setprio(1); MM(0); __builtin_amdgcn_s_setprio(0);
        VM7();                                   // A(kt).ag1 confirmed
        BAR();
        // ph1: (a1 x b0..5)
        SB1(kt + 2, 0, cur); SB1(kt + 2, 1, cur); SB1(kt + 2, 2, cur); SA(kt + 2, 0, cur);
        LDA(1, cur);
        __builtin_amdgcn_s_setprio(1); MM(2); __builtin_amdgcn_s_setprio(0);
        VM7();                                   // t(kt+1) first-5 confirmed
        BAR();
    }
#undef BAR
#undef VM7

    const int crow = m0 + wr * 64 + (l >> 4) * 4;
    const int ccol = n0 + wc * 96 + (l & 15);
#pragma unroll
    for (int i = 0; i < 4; i++) {
#pragma unroll
        for (int j = 0; j < 6; j++) {
            const int col = ccol + j * 16;
            const float sc = (col < scale_cols) ? scale : 1.f;
#pragma unroll
            for (int r = 0; r < 4; r++)
                C[(size_t)(crow + i * 16 + r) * ldc + col] = (OT)(acc[i][j][r] * sc);
        }
    }
}

// ---------------- deep-pipelined GEMM 256x128 (proven R12 version, for GEMM2) ----------------
template <typename OT>
__global__ __launch_bounds__(512, 1) void gemm256(const f16* __restrict__ A,
                                                  const f16* __restrict__ B,
                                                  OT* __restrict__ C,
                                                  int K, int ldc,
                                                  int scale_cols, float scale) {
    extern __shared__ char lds[];
    const int nt = K >> 6;
    const int tid = threadIdx.x;
    const int w  = tid >> 6;
    const int l  = tid & 63;
    const int wr = w >> 1;
    const int wc = w & 1;
    const int m0 = blockIdx.y * 256;
    const int n0 = blockIdx.x * 128;

    const int r0  = w * 8 + (l >> 3);
    const int csw = ((l & 7) ^ (l >> 3)) * 8;
    const f16* Ab = A + (size_t)(m0 + (r0 >> 5) * 64 + (r0 & 31)) * K + csw;
    const f16* Bb = B + (size_t)(n0 + (r0 >> 5) * 64 + (r0 & 31)) * K + csw;

    const int arow = wr * 32 + (l & 15);
    const int brow = wc * 32 + (l & 15);
    const int tcol = (l >> 4) * 16;
    const int sx   = (l & 7) << 4;

    f32x4 acc[4][4];
#pragma unroll
    for (int i = 0; i < 4; i++)
#pragma unroll
        for (int j = 0; j < 4; j++) acc[i][j] = (f32x4){0.f, 0.f, 0.f, 0.f};
    f16x8 a[2][2];
    f16x8 b[2][2][2];

    auto SA = [&](int kt, int ag, int buf) {
        const int kc = (kt < nt ? kt : nt - 1) << 6;
#pragma unroll
        for (int q = 0; q < 2; q++)
            __builtin_amdgcn_global_load_lds(
                (const __attribute__((address_space(1))) void*)(Ab + (size_t)(q * 128 + ag * 32) * K + kc),
                (__attribute__((address_space(3))) void*)(lds + buf * 32768 + (ag * 128 + q * 64 + w * 8) * 128),
                16, 0, 0);
    };
    auto SB = [&](int kt, int bg, int buf) {
        const int kc = (kt < nt ? kt : nt - 1) << 6;
        __builtin_amdgcn_global_load_lds(
            (const __attribute__((address_space(1))) void*)(Bb + (size_t)(bg * 32) * K + kc),
            (__attribute__((address_space(3))) void*)(lds + 65536 + buf * 16384 + (bg * 64 + w * 8) * 128),
            16, 0, 0);
    };
    auto LDA = [&](int ag, int buf) {
#pragma unroll
        for (int fr = 0; fr < 2; fr++)
#pragma unroll
            for (int ks = 0; ks < 2; ks++)
                a[fr][ks] = *reinterpret_cast<const f16x8*>(
                    lds + buf * 32768 + (ag * 128 + arow + fr * 16) * 128 + ((ks * 64 + tcol) ^ sx));
    };
    auto LDB = [&](int bg, int buf) {
#pragma unroll
        for (int fr = 0; fr < 2; fr++)
#pragma unroll
            for (int ks = 0; ks < 2; ks++)
                b[bg][fr][ks] = *reinterpret_cast<const f16x8*>(
                    lds + 65536 + buf * 16384 + (bg * 64 + brow + fr * 16) * 128 + ((ks * 64 + tcol) ^ sx));
    };
    auto MM = [&](int ai, int bg) {
#pragma unroll
        for (int fa = 0; fa < 2; fa++)
#pragma unroll
            for (int fb = 0; fb < 2; fb++)
#pragma unroll
                for (int ks = 0; ks < 2; ks++)
                    acc[ai + fa][bg * 2 + fb] = __builtin_amdgcn_mfma_f32_16x16x32_f16(
                        a[fa][ks], b[bg][fb][ks], acc[ai + fa][bg * 2 + fb], 0, 0, 0);
    };

#define BAR() do { asm volatile("" ::: "memory"); \
                   __builtin_amdgcn_s_barrier(); \
                   asm volatile("" ::: "memory"); } while (0)
#define VM6() asm volatile("s_waitcnt vmcnt(6)" ::: "memory")

    SB(0, 0, 0); SB(0, 1, 0); SA(0, 0, 0); SA(0, 1, 0);
    SB(1, 0, 1); SB(1, 1, 1); SA(1, 0, 1);
    asm volatile("s_waitcnt vmcnt(4)" ::: "memory");
    BAR();

    for (int kt = 0; kt < nt; kt++) {
        const int cur = kt & 1, nxt = cur ^ 1;
        SA(kt + 1, 1, nxt);
        LDA(0, cur); LDB(0, cur); LDB(1, cur);
        __builtin_amdgcn_s_setprio(1); MM(0, 0); MM(0, 1); __builtin_amdgcn_s_setprio(0);
        VM6();
        BAR();
        SB(kt + 2, 0, cur); SB(kt + 2, 1, cur); SA(kt + 2, 0, cur);
        LDA(1, cur);
        __builtin_amdgcn_s_setprio(1); MM(2, 0); MM(2, 1); __builtin_amdgcn_s_setprio(0);
        VM6();
        BAR();
    }
#undef BAR
#undef VM6

    const int crow = m0 + wr * 64 + (l >> 4) * 4;
    const int ccol = n0 + wc * 64 + (l & 15);
#pragma unroll
    for (int i = 0; i < 4; i++) {
#pragma unroll
        for (int j = 0; j < 4; j++) {
            const int col = ccol + j * 16;
            const float sc = (col < scale_cols) ? scale : 1.f;
#pragma unroll
            for (int r = 0; r < 4; r++)
                C[(size_t)(crow + i * 16 + r) * ldc + col] = (OT)(acc[i][j][r] * sc);
        }
    }
}

// ---------------- gate projection ----------------
__global__ __launch_bounds__(256) void gate_proj(const f16* __restrict__ xf,
                                                 const f16* __restrict__ wg16,
                                                 const float* __restrict__ big,
                                                 const float* __restrict__ bfg,
                                                 float* __restrict__ gates) {
    __shared__ float red[4][16][16];
    const int tid = threadIdx.x, w = tid >> 6, l = tid & 63;
    const int r0 = blockIdx.x * 16;
    const int kbase = w * 512 + (l >> 4) * 8;
    const f16* ap = xf + (size_t)(r0 + (l & 15)) * D_MODEL + kbase;
    const f16* bp = wg16 + (size_t)(l & 15) * D_MODEL + kbase;
    f32x4 acc = (f32x4){0.f, 0.f, 0.f, 0.f};
#pragma unroll
    for (int k0 = 0; k0 < 512; k0 += 32) {
        f16x8 af = *reinterpret_cast<const f16x8*>(ap + k0);
        f16x8 bf = *reinterpret_cast<const f16x8*>(bp + k0);
        acc = __builtin_amdgcn_mfma_f32_16x16x32_f16(af, bf, acc, 0, 0, 0);
    }
#pragma unroll
    for (int r = 0; r < 4; r++) red[w][(l >> 4) * 4 + r][l & 15] = acc[r];
    __syncthreads();
    const int row = tid >> 4, col = tid & 15;
    const float bias = (col & 1) ? bfg[col >> 1] : big[col >> 1];
    const float total = red[0][row][col] + red[1][row][col]
                      + red[2][row][col] + red[3][row][col] + bias;
    gates[(size_t)(r0 + row) * 16 + col] = total;
}

// ---------------- gate scan ----------------
__global__ __launch_bounds__(256) void gate_scan(const float* __restrict__ gates,
                                                 float4* __restrict__ gs4,
                                                 float2* __restrict__ gchunk,
                                                 float* __restrict__ mf) {
    const int bh = blockIdx.x;
    const int b = bh >> 3, h = bh & 7;
    const int tid = threadIdx.x;
    __shared__ float2 sif[S_LEN];
    __shared__ float2 comp[NCHUNK];
    for (int t = tid; t < S_LEN; t += 256) {
        const float2 pre = *reinterpret_cast<const float2*>(
            &gates[((size_t)b * S_LEN + t) * 16 + h * 2]);
        const float ic = 15.f * tanhf(pre.x * (1.f / 15.f));
        const float fc = 15.f * tanhf(pre.y * (1.f / 15.f));
        const float flog = fminf(fc, 0.f) - log1pf(expf(-fabsf(fc)));
        sif[t] = make_float2(ic, flog);
    }
    __syncthreads();
    if (tid < NCHUNK) {
        float bsum = 0.f, r = -1e30f;
        for (int s = 0; s < CHUNK; s++) {
            const float2 g = sif[tid * CHUNK + s];
            bsum += g.y;
            r = fmaxf(r, g.x - bsum);
        }
        comp[tid] = make_float2(bsum, r);
    }
    __syncthreads();
    if (tid < NCHUNK) {
        float m0 = 0.f;
        for (int c = 0; c < tid; c++) m0 = comp[c].x + fmaxf(m0, comp[c].y);
        float4* out = gs4 + (size_t)bh * S_LEN + tid * CHUNK;
        float bsum = 0.f, r = -1e30f;
        float mlast = 0.f, Alast = 0.f, alast = 0.f;
        for (int s = 0; s < CHUNK; s++) {
            const float2 g = sif[tid * CHUNK + s];
            bsum += g.y;
            const float uu = g.x - bsum;
            r = fmaxf(r, uu);
            const float mx = fmaxf(m0, r);
            const float mt = bsum + mx;
            const float At = -mx;
            const float al = expf(m0 + At);
            out[s] = make_float4(uu, At, al, expf(-mt));
            if (s == CHUNK - 1) { mlast = mt; Alast = At; alast = al; }
        }
        gchunk[bh * NCHUNK + tid] = make_float2(alast, Alast);
        if (tid == NCHUNK - 1) mf[bh] = mlast;
    }
}

// ---------------- phase A: intra attention + chunk summaries; h_intra -> hbuf (natural layout) ----------------
__global__ __launch_bounds__(256) void phaseA(const f16* __restrict__ qkvo,
                                              const float4* __restrict__ gs4,
                                              float* __restrict__ qn_intra,
                                              f16* __restrict__ Ubuf,
                                              f16* __restrict__ hbuf,
                                              float* __restrict__ UnB) {
    __shared__ f16 Kn[64][136];
    __shared__ f16 KgT[128][72];
    __shared__ f16 VT[256][72];     // reused as hs[64][260] after U
    __shared__ float u_s[64], A_t[64];
    __shared__ float qnp[4][64];
    f16 (*Pl)[72] = reinterpret_cast<f16(*)[72]>(&Kn[0][0]);
    f16* hs = &VT[0][0];            // [64 t][260 f16] stride chosen bank-conflict-free

    const int bid = blockIdx.x;
    const int bh = bid >> 5, ck = bid & 31;
    const int b = bh >> 3, h = bh & 7;
    const int tid = threadIdx.x;
    const int w = tid >> 6, l = tid & 63;

    const size_t rowbase = (size_t)b * S_LEN + ck * CHUNK;

    if (tid < 64) {
        float4 g = gs4[(size_t)bh * S_LEN + ck * CHUNK + tid];
        u_s[tid] = g.x; A_t[tid] = g.y;
    }
    const int sK = tid & 63, quad = tid >> 6;
    f16x8 kreg[4];
    {
        const f16* kp = qkvo + (rowbase + sK) * NCOL + KOFF + h * 128 + quad * 32;
#pragma unroll
        for (int i = 0; i < 4; i++) kreg[i] = *reinterpret_cast<const f16x8*>(kp + i * 8);
#pragma unroll
        for (int i = 0; i < 4; i++) *reinterpret_cast<f16x8*>(&Kn[sK][quad * 32 + i * 8]) = kreg[i];
    }
    {
        const f16* vp = qkvo + (rowbase + sK) * NCOL + VOFF + h * 256 + quad * 64;
#pragma unroll
        for (int i = 0; i < 8; i++) {
            f16x8 v = *reinterpret_cast<const f16x8*>(vp + i * 8);
#pragma unroll
            for (int e = 0; e < 8; e++) VT[quad * 64 + i * 8 + e][sK] = v[e];
        }
    }
    __syncthreads();
    {
        const float gam = __expf(u_s[sK] + A_t[63]);
#pragma unroll
        for (int i = 0; i < 4; i++)
#pragma unroll
            for (int e = 0; e < 8; e++)
                KgT[quad * 32 + i * 8 + e][sK] = (f16)(gam * (float)kreg[i][e]);
    }
    // S^T mfma
    f16x8 af[4];
#pragma unroll
    for (int kk = 0; kk < 4; kk++)
        af[kk] = *reinterpret_cast<const f16x8*>(&Kn[w * 16 + (l & 15)][kk * 32 + (l >> 4) * 8]);
    f32x4 st[4];
#pragma unroll
    for (int ct = 0; ct < 4; ct++) {
        st[ct] = (f32x4){0.f, 0.f, 0.f, 0.f};
#pragma unroll
        for (int kk = 0; kk < 4; kk++) {
            const f16* qp = qkvo + (rowbase + ct * 16 + (l & 15)) * NCOL + QOFF + h * 128 + kk * 32 + (l >> 4) * 8;
            f16x8 bf = *reinterpret_cast<const f16x8*>(qp);
            st[ct] = __builtin_amdgcn_mfma_f32_16x16x32_f16(af[kk], bf, st[ct], 0, 0, 0);
        }
    }
    __syncthreads();   // Kn dead -> Pl alias safe
#pragma unroll
    for (int ct = 0; ct < 4; ct++) {
        const int tloc = ct * 16 + (l & 15);
        const float At = A_t[tloc];
        float part = 0.f;
        f16x4 pk;
#pragma unroll
        for (int i = 0; i < 4; i++) {
            const int sloc = w * 16 + (l >> 4) * 4 + i;
            const float val = (sloc <= tloc) ? st[ct][i] * __expf(At + u_s[sloc]) : 0.f;
            part += val;
            pk[i] = (f16)val;
        }
        part += __shfl_xor(part, 16);
        part += __shfl_xor(part, 32);
        if ((l >> 4) == 0) qnp[w][tloc] = part;
        *reinterpret_cast<f16x4*>(&Pl[tloc][w * 16 + (l >> 4) * 4]) = pk;
    }
    __syncthreads();
    if (tid < 64)
        qn_intra[(size_t)bh * S_LEN + ck * CHUNK + tid] =
            qnp[0][tid] + qnp[1][tid] + qnp[2][tid] + qnp[3][tid];
    // PV: keep accs in registers (hacc[vt]); VT still needed by U
    f32x4 hacc[16];
    {
        f16x8 pa[2];
#pragma unroll
        for (int kk = 0; kk < 2; kk++)
            pa[kk] = *reinterpret_cast<const f16x8*>(&Pl[w * 16 + (l & 15)][kk * 32 + (l >> 4) * 8]);
#pragma unroll
        for (int vt = 0; vt < 16; vt++) {
            hacc[vt] = (f32x4){0.f, 0.f, 0.f, 0.f};
#pragma unroll
            for (int kk = 0; kk < 2; kk++) {
                f16x8 vb = *reinterpret_cast<const f16x8*>(&VT[vt * 16 + (l & 15)][kk * 32 + (l >> 4) * 8]);
                hacc[vt] = __builtin_amdgcn_mfma_f32_16x16x32_f16(pa[kk], vb, hacc[vt], 0, 0, 0);
            }
        }
    }
    // U (chunk summary, stored [dv][dq])
#pragma unroll
    for (int q = 0; q < 4; q++) {
        const int dvt = w * 4 + q;
        f16x8 vb[2];
#pragma unroll
        for (int kk = 0; kk < 2; kk++)
            vb[kk] = *reinterpret_cast<const f16x8*>(&VT[dvt * 16 + (l & 15)][kk * 32 + (l >> 4) * 8]);
#pragma unroll
        for (int dqt = 0; dqt < 8; dqt++) {
            f32x4 acc = (f32x4){0.f, 0.f, 0.f, 0.f};
#pragma unroll
            for (int kk = 0; kk < 2; kk++) {
                f16x8 ka = *reinterpret_cast<const f16x8*>(&KgT[dqt * 16 + (l & 15)][kk * 32 + (l >> 4) * 8]);
                acc = __builtin_amdgcn_mfma_f32_16x16x32_f16(ka, vb[kk], acc, 0, 0, 0);
            }
            f16x4 uk;
#pragma unroll
            for (int i = 0; i < 4; i++) uk[i] = (f16)acc[i];
            const size_t addr = (((size_t)bh * NCHUNK + ck) * 256 + dvt * 16 + (l & 15)) * 128
                              + dqt * 16 + (l >> 4) * 4;
            *reinterpret_cast<f16x4*>(&Ubuf[addr]) = uk;
        }
    }
    // Un row-sums
    {
        const int dq = tid >> 1, half = tid & 1;
        float sum = 0.f;
#pragma unroll
        for (int i = 0; i < 4; i++) {
            f16x8 kv = *reinterpret_cast<const f16x8*>(&KgT[dq][half * 32 + i * 8]);
#pragma unroll
            for (int e = 0; e < 8; e++) sum += (float)kv[e];
        }
        sum += __shfl_xor(sum, 1);
        if (half == 0) UnB[((size_t)bh * NCHUNK + ck) * 128 + dq] = sum;
    }
    // transpose h_intra through LDS (VT dead) -> coalesced hbuf write
    __syncthreads();
#pragma unroll
    for (int vt = 0; vt < 16; vt++)
#pragma unroll
        for (int i = 0; i < 4; i++)
            hs[(w * 16 + (l >> 4) * 4 + i) * 260 + vt * 16 + (l & 15)] = (f16)hacc[vt][i];
    __syncthreads();
#pragma unroll
    for (int k = 0; k < 8; k++) {
        const int id = tid + k * 256;
        const int row = id >> 5, c8 = id & 31;
        f16x8 v = *reinterpret_cast<const f16x8*>(&hs[row * 260 + c8 * 8]);
        *reinterpret_cast<f16x8*>(&hbuf[(rowbase + row) * D_MODEL + h * 256 + c8 * 8]) = v;
    }
}

// ---------------- phase B: inter-chunk C and n recurrences; updates hbuf in place ----------------
__global__ __launch_bounds__(256) void phaseB(const f16* __restrict__ qkvo,
                                              const f16* __restrict__ Ubuf,
                                              const float4* __restrict__ gs4,
                                              const float2* __restrict__ gchunk,
                                              const float* __restrict__ qn_intra,
                                              const float* __restrict__ UnB,
                                              f16* __restrict__ hbuf,
                                              float* __restrict__ Cf,
                                              float* __restrict__ nf) {
    const int bid = blockIdx.x;
    const int bh = bid >> 4, vt = bid & 15;
    const int b = bh >> 3, h = bh & 7;
    const int tid = threadIdx.x, w = tid >> 6, l = tid & 63;
    const int dv = vt * 16 + (l & 15);

    float c[4][8];
    float nn[4][8];
#pragma unroll
    for (int kk = 0; kk < 4; kk++)
#pragma unroll
        for (int j = 0; j < 8; j++) { c[kk][j] = 0.f; nn[kk][j] = 0.f; }

    for (int ck = 0; ck < NCHUNK; ck++) {
        f16x8 uf[4];
        const f16* ub = Ubuf + (((size_t)bh * NCHUNK + ck) * 256 + dv) * 128 + (l >> 4) * 8;
#pragma unroll
        for (int kk = 0; kk < 4; kk++) uf[kk] = *reinterpret_cast<const f16x8*>(ub + kk * 32);
        float un[4][8];
        const float* unp = UnB + ((size_t)bh * NCHUNK + ck) * 128 + (l >> 4) * 8;
#pragma unroll
        for (int kk = 0; kk < 4; kk++) {
            const float4 u0 = *reinterpret_cast<const float4*>(unp + kk * 32);
            const float4 u1 = *reinterpret_cast<const float4*>(unp + kk * 32 + 4);
            un[kk][0] = u0.x; un[kk][1] = u0.y; un[kk][2] = u0.z; un[kk][3] = u0.w;
            un[kk][4] = u1.x; un[kk][5] = u1.y; un[kk][6] = u1.z; un[kk][7] = u1.w;
        }
        const int t0 = ck * CHUNK + w * 16;
        f16x8 af[4];
        const f16* qp = qkvo + ((size_t)b * S_LEN + t0 + (l & 15)) * NCOL + QOFF + h * 128 + (l >> 4) * 8;
#pragma unroll
        for (int kk = 0; kk < 4; kk++) af[kk] = *reinterpret_cast<const f16x8*>(qp + kk * 32);
        f16x8 cf[4], cfn[4];
#pragma unroll
        for (int kk = 0; kk < 4; kk++)
#pragma unroll
            for (int j = 0; j < 8; j++) { cf[kk][j] = (f16)c[kk][j]; cfn[kk][j] = (f16)nn[kk][j]; }
        f32x4 H  = (f32x4){0.f, 0.f, 0.f, 0.f};
        f32x4 Hn = (f32x4){0.f, 0.f, 0.f, 0.f};
#pragma unroll
        for (int kk = 0; kk < 4; kk++) {
            H  = __builtin_amdgcn_mfma_f32_16x16x32_f16(af[kk], cf[kk],  H,  0, 0, 0);
            Hn = __builtin_amdgcn_mfma_f32_16x16x32_f16(af[kk], cfn[kk], Hn, 0, 0, 0);
        }
        const int tt = t0 + (l >> 4) * 4;
        const float4 qnI = *reinterpret_cast<const float4*>(&qn_intra[(size_t)bh * S_LEN + tt]);
        const float qni[4] = {qnI.x, qnI.y, qnI.z, qnI.w};
#pragma unroll
        for (int i = 0; i < 4; i++) {
            const float4 g = gs4[(size_t)bh * S_LEN + tt + i];
            const float al = g.z;
            const float qn = qni[i] + al * Hn[i];
            const float rd = 1.f / (fmaxf(fabsf(qn), g.w) + 1e-6f);
            const size_t hidx = ((size_t)b * S_LEN + tt + i) * D_MODEL + h * 256 + dv;
            const float hval = ((float)hbuf[hidx] + al * H[i]) * rd;
            hbuf[hidx] = (f16)hval;
        }
        const float F = gchunk[bh * NCHUNK + ck].x;
#pragma unroll
        for (int kk = 0; kk < 4; kk++)
#pragma unroll
            for (int j = 0; j < 8; j++) {
                c[kk][j]  = fmaf(F, c[kk][j],  (float)uf[kk][j]);
                nn[kk][j] = fmaf(F, nn[kk][j], un[kk][j]);
            }
    }
    if (w == 0) {
#pragma unroll
        for (int kk = 0; kk < 4; kk++)
#pragma unroll
            for (int j = 0; j < 8; j++) {
                const int dq = kk * 32 + (l >> 4) * 8 + j;
                Cf[((size_t)bh * 128 + dq) * 256 + dv] = c[kk][j];
            }
        if (vt == 0 && (l & 15) == 0) {
#pragma unroll
            for (int kk = 0; kk < 4; kk++)
#pragma unroll
                for (int j = 0; j < 8; j++) {
                    const int dq = kk * 32 + (l >> 4) * 8 + j;
                    nf[(size_t)bh * 128 + dq] = nn[kk][j];
                }
        }
    }
}

// ---------------- per-head layernorm * gamma * sigmoid(og), f16 in/out ----------------
__global__ __launch_bounds__(256) void norm_kernel(const f16* __restrict__ hbuf,
                                                   const f16* __restrict__ qkvo,
                                                   const float* __restrict__ gamma,
                                                   f16* __restrict__ hout) {
    const int row = blockIdx.x;
    const int tid = threadIdx.x;
    const int g = tid >> 5;
    const int l = tid & 31;
    const f16* hrow = hbuf + (size_t)row * D_MODEL + g * 256 + l * 8;
    f16x8 hv8 = *reinterpret_cast<const f16x8*>(hrow);
    float hv[8];
#pragma unroll
    for (int e = 0; e < 8; e++) hv[e] = (float)hv8[e];
    float s = 0.f, s2 = 0.f;
#pragma unroll
    for (int e = 0; e < 8; e++) { s += hv[e]; s2 += hv[e] * hv[e]; }
#pragma unroll
    for (int off = 1; off < 32; off <<= 1) {
        s  += __shfl_xor(s, off);
        s2 += __shfl_xor(s2, off);
    }
    const float mu  = s * (1.f / 256.f);
    const float var = s2 * (1.f / 256.f) - mu * mu;
    const float rs  = rsqrtf(var + 1e-6f);
    const f16* ogr = qkvo + (size_t)row * NCOL + OGOFF + g * 256 + l * 8;
    f16x8 og8 = *reinterpret_cast<const f16x8*>(ogr);
    const float* gam = gamma + g * 256 + l * 8;
    f16x8 o;
#pragma unroll
    for (int e = 0; e < 8; e++) {
        const float og  = (float)og8[e];
        const float sig = __builtin_amdgcn_rcpf(1.f + __expf(-og));
        const float hn  = (hv[e] - mu) * rs * gam[e];
        o[e] = (f16)(sig * hn);
    }
    *reinterpret_cast<f16x8*>(&hout[(size_t)row * D_MODEL + g * 256 + l * 8]) = o;
}

// ---------------- launch ----------------
extern "C" void kernel_launch(void* const* d_in, const int* in_sizes, int n_in,
                              void* d_out, int out_size, void* d_ws, size_t ws_size,
                              hipStream_t stream) {
    (void)in_sizes; (void)n_in; (void)out_size; (void)ws_size;
    const float* x     = (const float*)d_in[0];
    const float* Wq    = (const float*)d_in[1];
    const float* Wk    = (const float*)d_in[2];
    const float* Wv    = (const float*)d_in[3];
    const float* Wog   = (const float*)d_in[4];
    const float* Wig   = (const float*)d_in[5];
    const float* big   = (const float*)d_in[6];
    const float* Wfg   = (const float*)d_in[7];
    const float* bfg   = (const float*)d_in[8];
    const float* gamma = (const float*)d_in[9];
    const float* Wout  = (const float*)d_in[10];

    char* ws = (char*)d_ws;
    size_t off = 0;
    f16*    xf     = (f16*)(ws + off);    off += (size_t)NROWS * D_MODEL * 2;
    f16*    wcat   = (f16*)(ws + off);    off += (size_t)NCOL * D_MODEL * 2;
    f16*    woutf  = (f16*)(ws + off);    off += (size_t)D_MODEL * D_MODEL * 2;
    f16*    wg16   = (f16*)(ws + off);    off += (size_t)16 * D_MODEL * 2;
    f16*    qkvo   = (f16*)(ws + off);    off += (size_t)NROWS * NCOL * 2;
    float*  gates  = (float*)(ws + off);  off += (size_t)NROWS * 16 * 4;
    float4* gs4    = (float4*)(ws + off); off += (size_t)16 * S_LEN * 16;
    float2* gchunk = (float2*)(ws + off); off += (size_t)16 * NCHUNK * 8;
    float*  qn_i   = (float*)(ws + off);  off += (size_t)16 * S_LEN * 4;
    float*  UnB    = (float*)(ws + off);  off += (size_t)16 * NCHUNK * 128 * 4;
    f16*    Ubuf   = (f16*)(ws + off);    off += (size_t)16 * NCHUNK * 256 * 128 * 2;
    f16*    hbuf   = (f16*)(ws + off);    off += (size_t)NROWS * D_MODEL * 2;
    f16*    houtf  = xf;  // xf dead after GEMM1

    float* y  = (float*)d_out;
    float* Cf = y + (size_t)NROWS * D_MODEL;
    float* nf = Cf + (size_t)16 * 128 * 256;
    float* mf = nf + (size_t)16 * 128;

    // fused casts (x + weights + interleaved gate weights)
    cast_all<<<24608, 256, 0, stream>>>(x, Wq, Wk, Wv, Wog, Wig, Wfg, Wout,
                                        xf, wcat, woutf, wg16);

    // gate projection (MFMA, K-split) + chunk decomposition
    gate_proj<<<NROWS / 16, 256, 0, stream>>>(xf, wg16, big, bfg, gates);
    gate_scan<<<16, 256, 0, stream>>>(gates, gs4, gchunk, mf);

    // fused qkvo projection; 256x192 deep pipeline; grid (32,16)=512 = 2 exact CU rounds
    gemm192<f16><<<dim3(NCOL / 192, NROWS / 256), 512, 114688, stream>>>(
        xf, wcat, qkvo, D_MODEL, NCOL, 1024, 0.08838834764831845f);

    // chunkwise mLSTM (h_intra written straight into hbuf, updated in place by phaseB)
    phaseA<<<512, 256, 0, stream>>>(qkvo, gs4, qn_i, Ubuf, hbuf, UnB);
    phaseB<<<256, 256, 0, stream>>>(qkvo, Ubuf, gs4, gchunk, qn_i, UnB, hbuf, Cf, nf);

    // multihead norm + output gate
    norm_kernel<<<NROWS, 256, 0, stream>>>(hbuf, qkvo, gamma, houtf);

    // y = h_out @ Wout^T ; 256x128 pipeline, grid (16,16) = 1 exact CU round
    gemm256<float><<<dim3(D_MODEL / 128, NROWS / 256), 512, 98304, stream>>>(
        houtf, woutf, y, D_MODEL, D_MODEL, 0, 1.f);
}